// Round 15
// baseline (464.032 us; speedup 1.0000x reference)
//
#include <hip/hip_runtime.h>
#include <hip/hip_bf16.h>

// ============================================================================
// DIAGNOSTIC ROUND: exact R12 kernel bodies, wrapped in REP=5 deterministic
// repeats so phA/phB dispatches exceed the ~250us workspace-fill cutoff and
// surface in rocprof top-5 (VGPR/VALUBusy/Occupancy/FETCH + true time split).
// Output is bitwise identical to R12 (each rep recomputes the same values).
// ============================================================================
#define REP_A 5
#define REP_B 5

typedef __attribute__((ext_vector_type(8))) short bh8;   // 8 x bf16 (4 VGPR) MFMA A/B frag
typedef __attribute__((ext_vector_type(4))) float f4;    // 4 x f32 MFMA C/D frag

#define MFMA_BF16 __builtin_amdgcn_mfma_f32_16x16x32_bf16

// packed f32x2 -> bf16x2 (RNE), dst.lo = a, dst.hi = b  [T12 recipe]
__device__ __forceinline__ unsigned cvtpk(float a, float b) {
  unsigned r;
  asm("v_cvt_pk_bf16_f32 %0, %1, %2" : "=v"(r) : "v"(a), "v"(b));
  return r;
}
__device__ __forceinline__ bh8 mk_bh8(unsigned a, unsigned b, unsigned c, unsigned d) {
  uint4 u;
  u.x = a; u.y = b; u.z = c; u.w = d;
  return __builtin_bit_cast(bh8, u);
}

// tanh(x) = 1 - 2/(e^{2x}+1); clamp-free. 2 VALU + 2 trans.
__device__ __forceinline__ float fast_tanh(float x) {
  float e = __builtin_amdgcn_exp2f(x * 2.885390081777927f);
  return fmaf(-2.f, __builtin_amdgcn_rcpf(e + 1.f), 1.f);
}

// scalar RNE casts (cold paths only)
__device__ __forceinline__ short bf16hi(float f, float* hf) {
  __hip_bfloat16 h = __float2bfloat16(f);
  *hf = __bfloat162float(h);
  short s;
  __builtin_memcpy(&s, &h, 2);
  return s;
}
__device__ __forceinline__ short bf16s(float f) {
  __hip_bfloat16 h = __float2bfloat16(f);
  short s;
  __builtin_memcpy(&s, &h, 2);
  return s;
}

// d_hat layout: [b][i(30)][j(30)][h(32, bf16)] -> 64 B per (i,j) pair.

// ---------------------------------------------------------------------------
// Phase A (R12 body + REP_A repeat): d_hat = D@df_w+df_b -> global bf16.
// ---------------------------------------------------------------------------
__global__ __launch_bounds__(256, 4) void mdtnn_phA_mfma(
    const float* __restrict__ Dg, const int* __restrict__ sizesg,
    const float* __restrict__ dfwg, const float* __restrict__ dfbg,
    uint2* __restrict__ dhg)
{
  const int b = blockIdx.x, tid = threadIdx.x;
  const int w = tid >> 6, l = tid & 63;
  const int lr = l & 15, lc = l >> 4;
  const int n = sizesg[b];
  const int nn = n * n;
  const unsigned inv = (65536u + (unsigned)n - 1) / (unsigned)n;  // exact p/n for p<1024

  bh8 Ah[2][2], Al[2][2];
  #pragma unroll
  for (int ht = 0; ht < 2; ++ht) {
    const int h = ht * 16 + lr;
    #pragma unroll
    for (int kc = 0; kc < 2; ++kc) {
      #pragma unroll
      for (int e = 0; e < 8; ++e) {
        const int g = kc * 32 + lc * 8 + e;
        float v = (g < 56 && h < 30) ? dfwg[g * 30 + h] : 0.f;
        float hf;
        Ah[ht][kc][e] = bf16hi(v, &hf);
        Al[ht][kc][e] = bf16s(v - hf);
      }
    }
  }
  float dfbv[2][4];
  #pragma unroll
  for (int ht = 0; ht < 2; ++ht)
    #pragma unroll
    for (int e = 0; e < 4; ++e) {
      const int h = ht * 16 + lc * 4 + e;
      dfbv[ht][e] = (h < 30) ? dfbg[h] : 0.f;
    }

  const float* Db = Dg + (size_t)b * (30 * 30 * 56);
  uint2* dhb = dhg + (size_t)b * (30 * 30 * 8);
  const f4 z4 = {0.f, 0.f, 0.f, 0.f};

  for (int rep = 0; rep < REP_A; ++rep) {
    const int tiles = (nn + 15) >> 4;
    for (int t = w; t < tiles; t += 4) {
      const int p_raw = t * 16 + lr;
      const int p = min(p_raw, nn - 1);
      const int i = (int)(((unsigned)p * inv) >> 16);
      const int j = p - i * n;
      const int row = i * 30 + j;
      const float* Dp = Db + (size_t)row * 56;

      float4 q0 = *reinterpret_cast<const float4*>(Dp + lc * 8);
      float4 q1 = *reinterpret_cast<const float4*>(Dp + lc * 8 + 4);
      float4 q2 = {0.f, 0.f, 0.f, 0.f}, q3 = {0.f, 0.f, 0.f, 0.f};
      if (lc < 3) {
        q2 = *reinterpret_cast<const float4*>(Dp + 32 + lc * 8);
        q3 = *reinterpret_cast<const float4*>(Dp + 32 + lc * 8 + 4);
      }
      bh8 B0 = mk_bh8(cvtpk(q0.x, q0.y), cvtpk(q0.z, q0.w),
                      cvtpk(q1.x, q1.y), cvtpk(q1.z, q1.w));
      bh8 B1 = mk_bh8(cvtpk(q2.x, q2.y), cvtpk(q2.z, q2.w),
                      cvtpk(q3.x, q3.y), cvtpk(q3.z, q3.w));

      f4 a0 = z4, a1 = z4;
      a0 = MFMA_BF16(Al[0][0], B0, a0, 0, 0, 0);
      a0 = MFMA_BF16(Ah[0][0], B0, a0, 0, 0, 0);
      a0 = MFMA_BF16(Al[0][1], B1, a0, 0, 0, 0);
      a0 = MFMA_BF16(Ah[0][1], B1, a0, 0, 0, 0);
      a1 = MFMA_BF16(Al[1][0], B0, a1, 0, 0, 0);
      a1 = MFMA_BF16(Ah[1][0], B0, a1, 0, 0, 0);
      a1 = MFMA_BF16(Al[1][1], B1, a1, 0, 0, 0);
      a1 = MFMA_BF16(Ah[1][1], B1, a1, 0, 0, 0);

      if (p_raw < nn) {
        uint2 s0, s1;
        s0.x = cvtpk(a0[0] + dfbv[0][0], a0[1] + dfbv[0][1]);
        s0.y = cvtpk(a0[2] + dfbv[0][2], a0[3] + dfbv[0][3]);
        s1.x = cvtpk(a1[0] + dfbv[1][0], a1[1] + dfbv[1][1]);
        s1.y = cvtpk(a1[2] + dfbv[1][2], a1[3] + dfbv[1][3]);
        dhb[row * 8 + 0 * 4 + lc] = s0;
        dhb[row * 8 + 1 * 4 + lc] = s1;
      }
    }
  }
}

// ---------------------------------------------------------------------------
// Phase B (R12 body + REP_B repeat): one molecule per 128-thr block, 2 waves,
// duplicated C in regs, wave-private X1 bufs, halved i-range, 2 barriers/iter.
// ---------------------------------------------------------------------------
__global__ __launch_bounds__(128, 3) void mdtnn_phB5(
    const int* __restrict__ Zg, const int* __restrict__ sizesg,
    const float* __restrict__ embg, const float* __restrict__ cfwg,
    const float* __restrict__ cfbg, const float* __restrict__ fcwg,
    const float* __restrict__ w1g, const float* __restrict__ b1g,
    const float* __restrict__ w2g, const float* __restrict__ b2g,
    const unsigned* __restrict__ dhg, float* __restrict__ outg)
{
  const int tid = threadIdx.x;
  const int wid = tid >> 6, l = tid & 63;
  const int lr = l & 15, lc = l >> 4;
  const int bm = blockIdx.x;

  __shared__ __align__(16) float buf[2][32][36];   // per-wave bufs
  __shared__ __align__(16) float w1_s[32][16];
  __shared__ float b1_s[16], w2_s[16], wsum[2];

  for (int t = tid; t < 512; t += 128) {
    int k = t >> 4, c = t & 15;
    w1_s[k][c] = (k < 30 && c < 15) ? w1g[k * 15 + c] : 0.f;
  }
  if (tid < 16) {
    b1_s[tid] = (tid < 15) ? b1g[tid] : 0.f;
    w2_s[tid] = (tid < 15) ? w2g[tid] : 0.f;
  }

  const int n = sizesg[bm];
  float (*mybuf)[36] = buf[wid];

  float fcwF0[8], fcwF1[8];
  bh8 cfwB0h, cfwB0l, cfwB1h, cfwB1l;
  #pragma unroll
  for (int e = 0; e < 8; ++e) {
    const int kk = lc * 8 + e;
    const int c1 = lr + 16;
    fcwF0[e] = (kk < 30) ? fcwg[kk * 30 + lr] : 0.f;
    fcwF1[e] = (kk < 30 && c1 < 30) ? fcwg[kk * 30 + c1] : 0.f;
    float g0 = (kk < 30) ? cfwg[kk * 30 + lr] : 0.f;
    float g1 = (kk < 30 && c1 < 30) ? cfwg[kk * 30 + c1] : 0.f;
    float hf;
    cfwB0h[e] = bf16hi(g0, &hf);
    cfwB0l[e] = bf16s(g0 - hf);
    cfwB1h[e] = bf16hi(g1, &hf);
    cfwB1l[e] = bf16s(g1 - hf);
  }
  const float cfb0 = cfbg[lr];
  const float cfb1 = (lr + 16 < 30) ? cfbg[lr + 16] : 0.f;

  const unsigned* dhb = dhg + (size_t)bm * 14400;   // dwords
  const int n0 = (n + 1) >> 1;
  const int ibeg = wid ? n0 : 0;
  const int iend = wid ? n : n0;
  const bool j0ok = (lr < n), j1ok = (lr + 16 < n);
  const f4 z4 = {0.f, 0.f, 0.f, 0.f};

  for (int rep = 0; rep < REP_B; ++rep) {
    __syncthreads();   // bufs free (staging on rep 0; prev head afterwards)

    // C in registers, D-frag layout (duplicated in both waves)
    f4 C00, C01, C10, C11;
    #pragma unroll
    for (int e = 0; e < 4; ++e) {
      const int r0 = lc * 4 + e;
      const int r1 = 16 + lc * 4 + e;
      const int z0 = Zg[bm * 30 + r0];
      C00[e] = embg[z0 * 30 + lr];
      C01[e] = (lr + 16 < 30) ? embg[z0 * 30 + lr + 16] : 0.f;
      if (r1 < 30) {
        const int z1 = Zg[bm * 30 + r1];
        C10[e] = embg[z1 * 30 + lr];
        C11[e] = (lr + 16 < 30) ? embg[z1 * 30 + lr + 16] : 0.f;
      } else {
        C10[e] = 0.f;
        C11[e] = 0.f;
      }
    }

    for (int it = 0; it < 3; ++it) {
      // prefetch first dh of this wave's range (overlaps X1 compute)
      uint4 a0c = {0, 0, 0, 0}, a1c = {0, 0, 0, 0};
      if (ibeg < iend) {
        const unsigned* p = dhb + (size_t)ibeg * 480;
        if (j0ok) a0c = *reinterpret_cast<const uint4*>(p + lr * 16 + lc * 4);
        if (j1ok) a1c = *reinterpret_cast<const uint4*>(p + lr * 16 + 256 + lc * 4);
      }

      // ---- X1 (redundant per wave): spill C, A-frags, 12 MFMAs, write X1 ----
      #pragma unroll
      for (int e = 0; e < 4; ++e) {
        mybuf[lc * 4 + e][lr]           = C00[e];
        mybuf[lc * 4 + e][lr + 16]      = C01[e];
        mybuf[16 + lc * 4 + e][lr]      = C10[e];
        mybuf[16 + lc * 4 + e][lr + 16] = C11[e];
      }
      float cv0[8], cv1[8];
      *reinterpret_cast<float4*>(&cv0[0]) = *reinterpret_cast<const float4*>(&mybuf[lr][lc * 8]);
      *reinterpret_cast<float4*>(&cv0[4]) = *reinterpret_cast<const float4*>(&mybuf[lr][lc * 8 + 4]);
      *reinterpret_cast<float4*>(&cv1[0]) = *reinterpret_cast<const float4*>(&mybuf[16 + lr][lc * 8]);
      *reinterpret_cast<float4*>(&cv1[4]) = *reinterpret_cast<const float4*>(&mybuf[16 + lr][lc * 8 + 4]);

      unsigned h_[4], lo_[4];
      #pragma unroll
      for (int q = 0; q < 4; ++q) {
        unsigned hq = cvtpk(cv0[2 * q], cv0[2 * q + 1]);
        float f0 = __uint_as_float(hq << 16);
        float f1 = __uint_as_float(hq & 0xffff0000u);
        h_[q] = hq;
        lo_[q] = cvtpk(cv0[2 * q] - f0, cv0[2 * q + 1] - f1);
      }
      bh8 Ch0 = mk_bh8(h_[0], h_[1], h_[2], h_[3]);
      bh8 Cl0 = mk_bh8(lo_[0], lo_[1], lo_[2], lo_[3]);
      #pragma unroll
      for (int q = 0; q < 4; ++q) {
        unsigned hq = cvtpk(cv1[2 * q], cv1[2 * q + 1]);
        float f0 = __uint_as_float(hq << 16);
        float f1 = __uint_as_float(hq & 0xffff0000u);
        h_[q] = hq;
        lo_[q] = cvtpk(cv1[2 * q] - f0, cv1[2 * q + 1] - f1);
      }
      bh8 Ch1 = mk_bh8(h_[0], h_[1], h_[2], h_[3]);
      bh8 Cl1 = mk_bh8(lo_[0], lo_[1], lo_[2], lo_[3]);

      f4 d00 = MFMA_BF16(Ch0, cfwB0l, z4, 0, 0, 0);
      d00 = MFMA_BF16(Cl0, cfwB0h, d00, 0, 0, 0);
      d00 = MFMA_BF16(Ch0, cfwB0h, d00, 0, 0, 0);
      f4 d01 = MFMA_BF16(Ch0, cfwB1l, z4, 0, 0, 0);
      d01 = MFMA_BF16(Cl0, cfwB1h, d01, 0, 0, 0);
      d01 = MFMA_BF16(Ch0, cfwB1h, d01, 0, 0, 0);
      f4 d10 = MFMA_BF16(Ch1, cfwB0l, z4, 0, 0, 0);
      d10 = MFMA_BF16(Cl1, cfwB0h, d10, 0, 0, 0);
      d10 = MFMA_BF16(Ch1, cfwB0h, d10, 0, 0, 0);
      f4 d11 = MFMA_BF16(Ch1, cfwB1l, z4, 0, 0, 0);
      d11 = MFMA_BF16(Cl1, cfwB1h, d11, 0, 0, 0);
      d11 = MFMA_BF16(Ch1, cfwB1h, d11, 0, 0, 0);
      #pragma unroll
      for (int e = 0; e < 4; ++e) {
        mybuf[lc * 4 + e][lr]           = d00[e] + cfb0;
        mybuf[lc * 4 + e][lr + 16]      = d01[e] + cfb1;
        mybuf[16 + lc * 4 + e][lr]      = d10[e] + cfb0;
        mybuf[16 + lc * 4 + e][lr + 16] = d11[e] + cfb1;
      }

      // ---- i-loop over this wave's half (wave-private, one-ahead prefetch) ----
      f4 i00 = z4, i01 = z4, i10 = z4, i11 = z4;
      for (int i = ibeg; i < iend; ++i) {
        uint4 a0n = {0, 0, 0, 0}, a1n = {0, 0, 0, 0};
        if (i + 1 < iend) {
          const unsigned* p = dhb + (size_t)(i + 1) * 480;
          if (j0ok) a0n = *reinterpret_cast<const uint4*>(p + lr * 16 + lc * 4);
          if (j1ok) a1n = *reinterpret_cast<const uint4*>(p + lr * 16 + 256 + lc * 4);
        }
        float4 xA = *reinterpret_cast<const float4*>(&mybuf[i][lc * 8]);
        float4 xB = *reinterpret_cast<const float4*>(&mybuf[i][lc * 8 + 4]);
        float xv[8] = {xA.x, xA.y, xA.z, xA.w, xB.x, xB.y, xB.z, xB.w};
        bh8 W0 = mk_bh8(cvtpk(xv[0] * fcwF0[0], xv[1] * fcwF0[1]),
                        cvtpk(xv[2] * fcwF0[2], xv[3] * fcwF0[3]),
                        cvtpk(xv[4] * fcwF0[4], xv[5] * fcwF0[5]),
                        cvtpk(xv[6] * fcwF0[6], xv[7] * fcwF0[7]));
        bh8 W1 = mk_bh8(cvtpk(xv[0] * fcwF1[0], xv[1] * fcwF1[1]),
                        cvtpk(xv[2] * fcwF1[2], xv[3] * fcwF1[3]),
                        cvtpk(xv[4] * fcwF1[4], xv[5] * fcwF1[5]),
                        cvtpk(xv[6] * fcwF1[6], xv[7] * fcwF1[7]));
        const bh8 A0 = __builtin_bit_cast(bh8, a0c);
        const bh8 A1 = __builtin_bit_cast(bh8, a1c);
        f4 g;
        g = MFMA_BF16(A0, W0, z4, 0, 0, 0);
        #pragma unroll
        for (int e = 0; e < 4; ++e) i00[e] += fast_tanh(g[e]);
        g = MFMA_BF16(A0, W1, z4, 0, 0, 0);
        #pragma unroll
        for (int e = 0; e < 4; ++e) i01[e] += fast_tanh(g[e]);
        g = MFMA_BF16(A1, W0, z4, 0, 0, 0);
        #pragma unroll
        for (int e = 0; e < 4; ++e) i10[e] += fast_tanh(g[e]);
        g = MFMA_BF16(A1, W1, z4, 0, 0, 0);
        #pragma unroll
        for (int e = 0; e < 4; ++e) i11[e] += fast_tanh(g[e]);
        a0c = a0n;
        a1c = a1n;
      }

      // ---- inc exchange: write own, barrier, read both in fixed order ----
      #pragma unroll
      for (int e = 0; e < 4; ++e) {
        mybuf[lc * 4 + e][lr]           = i00[e];
        mybuf[lc * 4 + e][lr + 16]      = i01[e];
        mybuf[16 + lc * 4 + e][lr]      = i10[e];
        mybuf[16 + lc * 4 + e][lr + 16] = i11[e];
      }
      __syncthreads();
      #pragma unroll
      for (int e = 0; e < 4; ++e) {
        C00[e] += buf[0][lc * 4 + e][lr];
        C00[e] += buf[1][lc * 4 + e][lr];
        C01[e] += buf[0][lc * 4 + e][lr + 16];
        C01[e] += buf[1][lc * 4 + e][lr + 16];
        C10[e] += buf[0][16 + lc * 4 + e][lr];
        C10[e] += buf[1][16 + lc * 4 + e][lr];
        C11[e] += buf[0][16 + lc * 4 + e][lr + 16];
        C11[e] += buf[1][16 + lc * 4 + e][lr + 16];
      }
      __syncthreads();   // protect bufs before next iteration's X1 write
    }

    // ---- head: spill (identical) C to own buf; waves split the rows ----
    #pragma unroll
    for (int e = 0; e < 4; ++e) {
      mybuf[lc * 4 + e][lr]           = C00[e];
      mybuf[lc * 4 + e][lr + 16]      = C01[e];
      mybuf[16 + lc * 4 + e][lr]      = C10[e];
      mybuf[16 + lc * 4 + e][lr + 16] = C11[e];
    }
    float esum = 0.f;
    for (int t = l + wid * 64; t < n * 16; t += 128) {
      int j = t >> 4, c = t & 15;
      if (c < 15) {
        float a = b1_s[c];
        #pragma unroll
        for (int kc = 0; kc < 8; ++kc) {
          float4 c4 = *reinterpret_cast<const float4*>(&mybuf[j][kc * 4]);
          a = fmaf(c4.x, w1_s[kc * 4 + 0][c], a);
          a = fmaf(c4.y, w1_s[kc * 4 + 1][c], a);
          a = fmaf(c4.z, w1_s[kc * 4 + 2][c], a);
          a = fmaf(c4.w, w1_s[kc * 4 + 3][c], a);
        }
        esum += fast_tanh(a) * w2_s[c];
      }
    }
    #pragma unroll
    for (int off = 32; off; off >>= 1) esum += __shfl_down(esum, off);
    if (l == 0) wsum[wid] = esum;
    __syncthreads();
    if (tid == 0) outg[bm] = wsum[0] + wsum[1] + (float)n * b2g[0];
  }
}

extern "C" void kernel_launch(void* const* d_in, const int* in_sizes, int n_in,
                              void* d_out, int out_size, void* d_ws, size_t ws_size,
                              hipStream_t stream) {
  (void)in_sizes; (void)n_in; (void)ws_size;
  const int*   Z   = (const int*)d_in[0];
  const float* D   = (const float*)d_in[1];
  const int*   sz  = (const int*)d_in[2];
  const float* emb = (const float*)d_in[3];
  const float* dfw = (const float*)d_in[4];
  const float* dfb = (const float*)d_in[5];
  const float* cfw = (const float*)d_in[6];
  const float* cfb = (const float*)d_in[7];
  const float* fcw = (const float*)d_in[8];
  const float* w1  = (const float*)d_in[9];
  const float* b1  = (const float*)d_in[10];
  const float* w2  = (const float*)d_in[11];
  const float* b2  = (const float*)d_in[12];
  float* out = (float*)d_out;
  const int B = out_size;  // 2048

  mdtnn_phA_mfma<<<dim3(B), dim3(256), 0, stream>>>(D, sz, dfw, dfb, (uint2*)d_ws);
  mdtnn_phB5<<<dim3(B), dim3(128), 0, stream>>>(Z, sz, emb, cfw, cfb, fcw,
                                                w1, b1, w2, b2,
                                                (const unsigned*)d_ws, out);
}

// Round 16
// 162.978 us; speedup vs baseline: 2.8472x; 2.8472x over previous
//
#include <hip/hip_runtime.h>
#include <hip/hip_bf16.h>

typedef __attribute__((ext_vector_type(8))) short bh8;   // 8 x bf16 (4 VGPR) MFMA A/B frag
typedef __attribute__((ext_vector_type(4))) float f4;    // 4 x f32 MFMA C/D frag

#define MFMA_BF16 __builtin_amdgcn_mfma_f32_16x16x32_bf16

// packed f32x2 -> bf16x2 (RNE), dst.lo = a, dst.hi = b  [T12 recipe]
__device__ __forceinline__ unsigned cvtpk(float a, float b) {
  unsigned r;
  asm("v_cvt_pk_bf16_f32 %0, %1, %2" : "=v"(r) : "v"(a), "v"(b));
  return r;
}
__device__ __forceinline__ bh8 mk_bh8(unsigned a, unsigned b, unsigned c, unsigned d) {
  uint4 u;
  u.x = a; u.y = b; u.z = c; u.w = d;
  return __builtin_bit_cast(bh8, u);
}

// tanh(x) = 1 - 2/(e^{2x}+1); clamp-free. 2 VALU + 2 trans.
__device__ __forceinline__ float fast_tanh(float x) {
  float e = __builtin_amdgcn_exp2f(x * 2.885390081777927f);
  return fmaf(-2.f, __builtin_amdgcn_rcpf(e + 1.f), 1.f);
}

// scalar RNE casts (cold paths only)
__device__ __forceinline__ short bf16hi(float f, float* hf) {
  __hip_bfloat16 h = __float2bfloat16(f);
  *hf = __bfloat162float(h);
  short s;
  __builtin_memcpy(&s, &h, 2);
  return s;
}
__device__ __forceinline__ short bf16s(float f) {
  __hip_bfloat16 h = __float2bfloat16(f);
  short s;
  __builtin_memcpy(&s, &h, 2);
  return s;
}

// d_hat layout: [b][i(30)][j(30)][h(32, bf16)] -> 64 B per (i,j) pair (global).

// ---------------------------------------------------------------------------
// FUSED: one molecule per 256-thread block (4 waves).
//  Part 1 (R12 phA body): dh = D@df_w+df_b -> GLOBAL (this block's slice only;
//          re-read below is same-CU L2-hot). __syncthreads makes it visible.
//  Part 2 (phB, 4-wave): C duplicated in regs in all 4 waves; per iteration
//          each wave redundantly computes X1 into its OWN LDS buf (no barrier
//          needed before i-loop), runs a QUARTER of the i-range, then a 4-buf
//          inc exchange (2 barriers/iter) applies identical-order C updates.
//  launch_bounds(256,5): 5 blocks/CU resident (20 waves/CU) + 768 of 2048
//  blocks stream in as CUs free -> HW-level molecule-granular load balancing
//  (R15 counters: frozen residency + n-imbalance caused the 17.7% occupancy).
// ---------------------------------------------------------------------------
__global__ __launch_bounds__(256, 5) void mdtnn_fused1(
    const int* __restrict__ Zg, const float* __restrict__ Dg,
    const int* __restrict__ sizesg, const float* __restrict__ embg,
    const float* __restrict__ dfwg, const float* __restrict__ dfbg,
    const float* __restrict__ cfwg, const float* __restrict__ cfbg,
    const float* __restrict__ fcwg, const float* __restrict__ w1g,
    const float* __restrict__ b1g, const float* __restrict__ w2g,
    const float* __restrict__ b2g, uint2* __restrict__ dhg,
    float* __restrict__ outg)
{
  const int bm = blockIdx.x, tid = threadIdx.x;
  const int wid = tid >> 6, l = tid & 63;
  const int lr = l & 15, lc = l >> 4;
  const int n = sizesg[bm];
  const int nn = n * n;

  __shared__ __align__(16) float buf[4][32][36];   // per-wave bufs (X1/incs)
  __shared__ __align__(16) float w1_s[30][16];
  __shared__ float b1_s[16], w2_s[16], wsum[4];

  for (int t = tid; t < 480; t += 256) {
    int k = t >> 4, c = t & 15;
    w1_s[k][c] = (c < 15) ? w1g[k * 15 + c] : 0.f;
  }
  if (tid < 16) {
    b1_s[tid] = (tid < 15) ? b1g[tid] : 0.f;
    w2_s[tid] = (tid < 15) ? w2g[tid] : 0.f;
  }

  // ======================= Part 1: dh (R12 phA body) =======================
  {
    const unsigned inv = (65536u + (unsigned)n - 1) / (unsigned)n;  // exact p/n, p<1024
    bh8 Ah[2][2], Al[2][2];
    #pragma unroll
    for (int ht = 0; ht < 2; ++ht) {
      const int h = ht * 16 + lr;
      #pragma unroll
      for (int kc = 0; kc < 2; ++kc) {
        #pragma unroll
        for (int e = 0; e < 8; ++e) {
          const int g = kc * 32 + lc * 8 + e;
          float v = (g < 56 && h < 30) ? dfwg[g * 30 + h] : 0.f;
          float hf;
          Ah[ht][kc][e] = bf16hi(v, &hf);
          Al[ht][kc][e] = bf16s(v - hf);
        }
      }
    }
    float dfbv[2][4];
    #pragma unroll
    for (int ht = 0; ht < 2; ++ht)
      #pragma unroll
      for (int e = 0; e < 4; ++e) {
        const int h = ht * 16 + lc * 4 + e;
        dfbv[ht][e] = (h < 30) ? dfbg[h] : 0.f;
      }

    const float* Db = Dg + (size_t)bm * (30 * 30 * 56);
    uint2* dhb = dhg + (size_t)bm * (30 * 30 * 8);
    const f4 z4 = {0.f, 0.f, 0.f, 0.f};

    const int tiles = (nn + 15) >> 4;
    for (int t = wid; t < tiles; t += 4) {
      const int p_raw = t * 16 + lr;
      const int p = min(p_raw, nn - 1);
      const int i = (int)(((unsigned)p * inv) >> 16);
      const int j = p - i * n;
      const int row = i * 30 + j;
      const float* Dp = Db + (size_t)row * 56;

      float4 q0 = *reinterpret_cast<const float4*>(Dp + lc * 8);
      float4 q1 = *reinterpret_cast<const float4*>(Dp + lc * 8 + 4);
      float4 q2 = {0.f, 0.f, 0.f, 0.f}, q3 = {0.f, 0.f, 0.f, 0.f};
      if (lc < 3) {
        q2 = *reinterpret_cast<const float4*>(Dp + 32 + lc * 8);
        q3 = *reinterpret_cast<const float4*>(Dp + 32 + lc * 8 + 4);
      }
      bh8 B0 = mk_bh8(cvtpk(q0.x, q0.y), cvtpk(q0.z, q0.w),
                      cvtpk(q1.x, q1.y), cvtpk(q1.z, q1.w));
      bh8 B1 = mk_bh8(cvtpk(q2.x, q2.y), cvtpk(q2.z, q2.w),
                      cvtpk(q3.x, q3.y), cvtpk(q3.z, q3.w));

      f4 a0 = z4, a1 = z4;
      a0 = MFMA_BF16(Al[0][0], B0, a0, 0, 0, 0);
      a0 = MFMA_BF16(Ah[0][0], B0, a0, 0, 0, 0);
      a0 = MFMA_BF16(Al[0][1], B1, a0, 0, 0, 0);
      a0 = MFMA_BF16(Ah[0][1], B1, a0, 0, 0, 0);
      a1 = MFMA_BF16(Al[1][0], B0, a1, 0, 0, 0);
      a1 = MFMA_BF16(Ah[1][0], B0, a1, 0, 0, 0);
      a1 = MFMA_BF16(Al[1][1], B1, a1, 0, 0, 0);
      a1 = MFMA_BF16(Ah[1][1], B1, a1, 0, 0, 0);

      if (p_raw < nn) {
        uint2 s0, s1;
        s0.x = cvtpk(a0[0] + dfbv[0][0], a0[1] + dfbv[0][1]);
        s0.y = cvtpk(a0[2] + dfbv[0][2], a0[3] + dfbv[0][3]);
        s1.x = cvtpk(a1[0] + dfbv[1][0], a1[1] + dfbv[1][1]);
        s1.y = cvtpk(a1[2] + dfbv[1][2], a1[3] + dfbv[1][3]);
        dhb[row * 8 + 0 * 4 + lc] = s0;
        dhb[row * 8 + 1 * 4 + lc] = s1;
      }
    }
  }

  // ================== Part 2: message passing (4-wave phB) ==================
  float (*mybuf)[36] = buf[wid];

  float fcwF0[8], fcwF1[8];
  bh8 cfwB0h, cfwB0l, cfwB1h, cfwB1l;
  #pragma unroll
  for (int e = 0; e < 8; ++e) {
    const int kk = lc * 8 + e;
    const int c1 = lr + 16;
    fcwF0[e] = (kk < 30) ? fcwg[kk * 30 + lr] : 0.f;
    fcwF1[e] = (kk < 30 && c1 < 30) ? fcwg[kk * 30 + c1] : 0.f;
    float g0 = (kk < 30) ? cfwg[kk * 30 + lr] : 0.f;
    float g1 = (kk < 30 && c1 < 30) ? cfwg[kk * 30 + c1] : 0.f;
    float hf;
    cfwB0h[e] = bf16hi(g0, &hf);
    cfwB0l[e] = bf16s(g0 - hf);
    cfwB1h[e] = bf16hi(g1, &hf);
    cfwB1l[e] = bf16s(g1 - hf);
  }
  const float cfb0 = cfbg[lr];
  const float cfb1 = (lr + 16 < 30) ? cfbg[lr + 16] : 0.f;

  // C in registers, D-frag layout (duplicated in all 4 waves)
  f4 C00, C01, C10, C11;
  #pragma unroll
  for (int e = 0; e < 4; ++e) {
    const int r0 = lc * 4 + e;
    const int r1 = 16 + lc * 4 + e;
    const int z0 = Zg[bm * 30 + r0];
    C00[e] = embg[z0 * 30 + lr];
    C01[e] = (lr + 16 < 30) ? embg[z0 * 30 + lr + 16] : 0.f;
    if (r1 < 30) {
      const int z1 = Zg[bm * 30 + r1];
      C10[e] = embg[z1 * 30 + lr];
      C11[e] = (lr + 16 < 30) ? embg[z1 * 30 + lr + 16] : 0.f;
    } else {
      C10[e] = 0.f;
      C11[e] = 0.f;
    }
  }

  const unsigned* dh_dw = (const unsigned*)(dhg) + (size_t)bm * 14400;  // dwords
  const int ibeg = (n * wid) >> 2;
  const int iend = (n * (wid + 1)) >> 2;
  const bool j0ok = (lr < n), j1ok = (lr + 16 < n);
  const f4 z4 = {0.f, 0.f, 0.f, 0.f};

  __syncthreads();   // dh visible (vmcnt drained), staging done, bufs free

  for (int it = 0; it < 3; ++it) {
    // prefetch first dh of this wave's quarter (overlaps X1 compute)
    uint4 a0c = {0, 0, 0, 0}, a1c = {0, 0, 0, 0};
    if (ibeg < iend) {
      const unsigned* p = dh_dw + (size_t)ibeg * 480;
      if (j0ok) a0c = *reinterpret_cast<const uint4*>(p + lr * 16 + lc * 4);
      if (j1ok) a1c = *reinterpret_cast<const uint4*>(p + lr * 16 + 256 + lc * 4);
    }

    // ---- X1 (redundant per wave, own buf): spill C, A-frags, 12 MFMAs ----
    #pragma unroll
    for (int e = 0; e < 4; ++e) {
      mybuf[lc * 4 + e][lr]           = C00[e];
      mybuf[lc * 4 + e][lr + 16]      = C01[e];
      mybuf[16 + lc * 4 + e][lr]      = C10[e];
      mybuf[16 + lc * 4 + e][lr + 16] = C11[e];
    }
    float cv0[8], cv1[8];
    *reinterpret_cast<float4*>(&cv0[0]) = *reinterpret_cast<const float4*>(&mybuf[lr][lc * 8]);
    *reinterpret_cast<float4*>(&cv0[4]) = *reinterpret_cast<const float4*>(&mybuf[lr][lc * 8 + 4]);
    *reinterpret_cast<float4*>(&cv1[0]) = *reinterpret_cast<const float4*>(&mybuf[16 + lr][lc * 8]);
    *reinterpret_cast<float4*>(&cv1[4]) = *reinterpret_cast<const float4*>(&mybuf[16 + lr][lc * 8 + 4]);

    unsigned h_[4], lo_[4];
    #pragma unroll
    for (int q = 0; q < 4; ++q) {
      unsigned hq = cvtpk(cv0[2 * q], cv0[2 * q + 1]);
      float f0 = __uint_as_float(hq << 16);
      float f1 = __uint_as_float(hq & 0xffff0000u);
      h_[q] = hq;
      lo_[q] = cvtpk(cv0[2 * q] - f0, cv0[2 * q + 1] - f1);
    }
    bh8 Ch0 = mk_bh8(h_[0], h_[1], h_[2], h_[3]);
    bh8 Cl0 = mk_bh8(lo_[0], lo_[1], lo_[2], lo_[3]);
    #pragma unroll
    for (int q = 0; q < 4; ++q) {
      unsigned hq = cvtpk(cv1[2 * q], cv1[2 * q + 1]);
      float f0 = __uint_as_float(hq << 16);
      float f1 = __uint_as_float(hq & 0xffff0000u);
      h_[q] = hq;
      lo_[q] = cvtpk(cv1[2 * q] - f0, cv1[2 * q + 1] - f1);
    }
    bh8 Ch1 = mk_bh8(h_[0], h_[1], h_[2], h_[3]);
    bh8 Cl1 = mk_bh8(lo_[0], lo_[1], lo_[2], lo_[3]);

    f4 d00 = MFMA_BF16(Ch0, cfwB0l, z4, 0, 0, 0);
    d00 = MFMA_BF16(Cl0, cfwB0h, d00, 0, 0, 0);
    d00 = MFMA_BF16(Ch0, cfwB0h, d00, 0, 0, 0);
    f4 d01 = MFMA_BF16(Ch0, cfwB1l, z4, 0, 0, 0);
    d01 = MFMA_BF16(Cl0, cfwB1h, d01, 0, 0, 0);
    d01 = MFMA_BF16(Ch0, cfwB1h, d01, 0, 0, 0);
    f4 d10 = MFMA_BF16(Ch1, cfwB0l, z4, 0, 0, 0);
    d10 = MFMA_BF16(Cl1, cfwB0h, d10, 0, 0, 0);
    d10 = MFMA_BF16(Ch1, cfwB0h, d10, 0, 0, 0);
    f4 d11 = MFMA_BF16(Ch1, cfwB1l, z4, 0, 0, 0);
    d11 = MFMA_BF16(Cl1, cfwB1h, d11, 0, 0, 0);
    d11 = MFMA_BF16(Ch1, cfwB1h, d11, 0, 0, 0);
    #pragma unroll
    for (int e = 0; e < 4; ++e) {
      mybuf[lc * 4 + e][lr]           = d00[e] + cfb0;
      mybuf[lc * 4 + e][lr + 16]      = d01[e] + cfb1;
      mybuf[16 + lc * 4 + e][lr]      = d10[e] + cfb0;
      mybuf[16 + lc * 4 + e][lr + 16] = d11[e] + cfb1;
    }

    // ---- i-loop over this wave's quarter (wave-private, one-ahead prefetch) ----
    f4 i00 = z4, i01 = z4, i10 = z4, i11 = z4;
    for (int i = ibeg; i < iend; ++i) {
      uint4 a0n = {0, 0, 0, 0}, a1n = {0, 0, 0, 0};
      if (i + 1 < iend) {
        const unsigned* p = dh_dw + (size_t)(i + 1) * 480;
        if (j0ok) a0n = *reinterpret_cast<const uint4*>(p + lr * 16 + lc * 4);
        if (j1ok) a1n = *reinterpret_cast<const uint4*>(p + lr * 16 + 256 + lc * 4);
      }
      float4 xA = *reinterpret_cast<const float4*>(&mybuf[i][lc * 8]);
      float4 xB = *reinterpret_cast<const float4*>(&mybuf[i][lc * 8 + 4]);
      float xv[8] = {xA.x, xA.y, xA.z, xA.w, xB.x, xB.y, xB.z, xB.w};
      bh8 W0 = mk_bh8(cvtpk(xv[0] * fcwF0[0], xv[1] * fcwF0[1]),
                      cvtpk(xv[2] * fcwF0[2], xv[3] * fcwF0[3]),
                      cvtpk(xv[4] * fcwF0[4], xv[5] * fcwF0[5]),
                      cvtpk(xv[6] * fcwF0[6], xv[7] * fcwF0[7]));
      bh8 W1 = mk_bh8(cvtpk(xv[0] * fcwF1[0], xv[1] * fcwF1[1]),
                      cvtpk(xv[2] * fcwF1[2], xv[3] * fcwF1[3]),
                      cvtpk(xv[4] * fcwF1[4], xv[5] * fcwF1[5]),
                      cvtpk(xv[6] * fcwF1[6], xv[7] * fcwF1[7]));
      const bh8 A0 = __builtin_bit_cast(bh8, a0c);
      const bh8 A1 = __builtin_bit_cast(bh8, a1c);
      f4 g;
      g = MFMA_BF16(A0, W0, z4, 0, 0, 0);
      #pragma unroll
      for (int e = 0; e < 4; ++e) i00[e] += fast_tanh(g[e]);
      g = MFMA_BF16(A0, W1, z4, 0, 0, 0);
      #pragma unroll
      for (int e = 0; e < 4; ++e) i01[e] += fast_tanh(g[e]);
      g = MFMA_BF16(A1, W0, z4, 0, 0, 0);
      #pragma unroll
      for (int e = 0; e < 4; ++e) i10[e] += fast_tanh(g[e]);
      g = MFMA_BF16(A1, W1, z4, 0, 0, 0);
      #pragma unroll
      for (int e = 0; e < 4; ++e) i11[e] += fast_tanh(g[e]);
      a0c = a0n;
      a1c = a1n;
    }

    // ---- inc exchange: write own buf, barrier, read all 4 in fixed order ----
    #pragma unroll
    for (int e = 0; e < 4; ++e) {
      mybuf[lc * 4 + e][lr]           = i00[e];
      mybuf[lc * 4 + e][lr + 16]      = i01[e];
      mybuf[16 + lc * 4 + e][lr]      = i10[e];
      mybuf[16 + lc * 4 + e][lr + 16] = i11[e];
    }
    __syncthreads();
    #pragma unroll
    for (int wq = 0; wq < 4; ++wq) {
      #pragma unroll
      for (int e = 0; e < 4; ++e) {
        C00[e] += buf[wq][lc * 4 + e][lr];
        C01[e] += buf[wq][lc * 4 + e][lr + 16];
        C10[e] += buf[wq][16 + lc * 4 + e][lr];
        C11[e] += buf[wq][16 + lc * 4 + e][lr + 16];
      }
    }
    __syncthreads();   // protect bufs before next iteration's X1 write
  }

  // ---- head: spill (identical) C to own buf; 4 waves split the rows ----
  #pragma unroll
  for (int e = 0; e < 4; ++e) {
    mybuf[lc * 4 + e][lr]           = C00[e];
    mybuf[lc * 4 + e][lr + 16]      = C01[e];
    mybuf[16 + lc * 4 + e][lr]      = C10[e];
    mybuf[16 + lc * 4 + e][lr + 16] = C11[e];
  }
  float esum = 0.f;
  for (int t = l + wid * 64; t < n * 16; t += 256) {
    int j = t >> 4, c = t & 15;
    if (c < 15) {
      float a = b1_s[c];
      #pragma unroll
      for (int kc = 0; kc < 8; ++kc) {
        float4 c4 = *reinterpret_cast<const float4*>(&mybuf[j][kc * 4]);
        a = fmaf(c4.x, w1_s[min(kc * 4 + 0, 29)][c], a);
        a = fmaf(c4.y, w1_s[min(kc * 4 + 1, 29)][c], a);
        a = fmaf(c4.z, w1_s[min(kc * 4 + 2, 29)][c], a);
        a = fmaf(c4.w, w1_s[min(kc * 4 + 3, 29)][c], a);
      }
      esum += fast_tanh(a) * w2_s[c];
    }
  }
  #pragma unroll
  for (int off = 32; off; off >>= 1) esum += __shfl_down(esum, off);
  if (l == 0) wsum[wid] = esum;
  __syncthreads();
  if (tid == 0)
    outg[bm] = wsum[0] + wsum[1] + wsum[2] + wsum[3] + (float)n * b2g[0];
}

extern "C" void kernel_launch(void* const* d_in, const int* in_sizes, int n_in,
                              void* d_out, int out_size, void* d_ws, size_t ws_size,
                              hipStream_t stream) {
  (void)in_sizes; (void)n_in; (void)ws_size;
  const int*   Z   = (const int*)d_in[0];
  const float* D   = (const float*)d_in[1];
  const int*   sz  = (const int*)d_in[2];
  const float* emb = (const float*)d_in[3];
  const float* dfw = (const float*)d_in[4];
  const float* dfb = (const float*)d_in[5];
  const float* cfw = (const float*)d_in[6];
  const float* cfb = (const float*)d_in[7];
  const float* fcw = (const float*)d_in[8];
  const float* w1  = (const float*)d_in[9];
  const float* b1  = (const float*)d_in[10];
  const float* w2  = (const float*)d_in[11];
  const float* b2  = (const float*)d_in[12];
  float* out = (float*)d_out;
  const int B = out_size;  // 2048

  mdtnn_fused1<<<dim3(B), dim3(256), 0, stream>>>(Z, D, sz, emb, dfw, dfb, cfw, cfb,
                                                  fcw, w1, b1, w2, b2,
                                                  (uint2*)d_ws, out);
}

// Round 17
// 140.944 us; speedup vs baseline: 3.2923x; 1.1563x over previous
//
#include <hip/hip_runtime.h>
#include <hip/hip_bf16.h>

typedef __attribute__((ext_vector_type(8))) short bh8;   // 8 x bf16 (4 VGPR) MFMA A/B frag
typedef __attribute__((ext_vector_type(4))) float f4;    // 4 x f32 MFMA C/D frag

#define MFMA_BF16 __builtin_amdgcn_mfma_f32_16x16x32_bf16

// packed f32x2 -> bf16x2 (RNE), dst.lo = a, dst.hi = b  [T12 recipe]
__device__ __forceinline__ unsigned cvtpk(float a, float b) {
  unsigned r;
  asm("v_cvt_pk_bf16_f32 %0, %1, %2" : "=v"(r) : "v"(a), "v"(b));
  return r;
}
__device__ __forceinline__ bh8 mk_bh8(unsigned a, unsigned b, unsigned c, unsigned d) {
  uint4 u;
  u.x = a; u.y = b; u.z = c; u.w = d;
  return __builtin_bit_cast(bh8, u);
}

// tanh(x) = 1 - 2/(e^{2x}+1); clamp-free. 2 VALU + 2 trans.
__device__ __forceinline__ float fast_tanh(float x) {
  float e = __builtin_amdgcn_exp2f(x * 2.885390081777927f);
  return fmaf(-2.f, __builtin_amdgcn_rcpf(e + 1.f), 1.f);
}

// scalar RNE casts (cold paths only)
__device__ __forceinline__ short bf16hi(float f, float* hf) {
  __hip_bfloat16 h = __float2bfloat16(f);
  *hf = __bfloat162float(h);
  short s;
  __builtin_memcpy(&s, &h, 2);
  return s;
}
__device__ __forceinline__ short bf16s(float f) {
  __hip_bfloat16 h = __float2bfloat16(f);
  short s;
  __builtin_memcpy(&s, &h, 2);
  return s;
}

// ---------------------------------------------------------------------------
// LPT rank kernel: perm = molecules sorted by n DESC (stable by index).
// rank[b] = #{k: n[k]>n[b]} + #{k<b: n[k]==n[b]}; perm[rank]=b. Deterministic.
// ---------------------------------------------------------------------------
__global__ __launch_bounds__(256) void mdtnn_rank(
    const int* __restrict__ sizesg, int Bn, int* __restrict__ perm)
{
  __shared__ int ns[2048];
  for (int t = threadIdx.x; t < Bn; t += 256) ns[t] = sizesg[t];
  __syncthreads();
  const int b = blockIdx.x * 256 + threadIdx.x;
  if (b < Bn) {
    const int nb = ns[b];
    int r = 0;
    for (int k = 0; k < Bn; ++k) {
      const int nk = ns[k];
      r += (nk > nb) | ((nk == nb) & (k < b));
    }
    perm[r] = b;
  }
}

// d_hat layout: [b][i(30)][j(30)][h(32, bf16)] -> 64 B per (i,j) pair.

// ---------------------------------------------------------------------------
// Phase A (exact R12 body; molecule = perm[blockIdx.x] for LPT order).
// ---------------------------------------------------------------------------
__global__ __launch_bounds__(256, 4) void mdtnn_phA_mfma(
    const float* __restrict__ Dg, const int* __restrict__ sizesg,
    const float* __restrict__ dfwg, const float* __restrict__ dfbg,
    uint2* __restrict__ dhg, const int* __restrict__ perm)
{
  const int b = perm[blockIdx.x];
  const int tid = threadIdx.x;
  const int w = tid >> 6, l = tid & 63;
  const int lr = l & 15, lc = l >> 4;
  const int n = sizesg[b];
  const int nn = n * n;
  const unsigned inv = (65536u + (unsigned)n - 1) / (unsigned)n;  // exact p/n for p<1024

  bh8 Ah[2][2], Al[2][2];
  #pragma unroll
  for (int ht = 0; ht < 2; ++ht) {
    const int h = ht * 16 + lr;
    #pragma unroll
    for (int kc = 0; kc < 2; ++kc) {
      #pragma unroll
      for (int e = 0; e < 8; ++e) {
        const int g = kc * 32 + lc * 8 + e;
        float v = (g < 56 && h < 30) ? dfwg[g * 30 + h] : 0.f;
        float hf;
        Ah[ht][kc][e] = bf16hi(v, &hf);
        Al[ht][kc][e] = bf16s(v - hf);
      }
    }
  }
  float dfbv[2][4];
  #pragma unroll
  for (int ht = 0; ht < 2; ++ht)
    #pragma unroll
    for (int e = 0; e < 4; ++e) {
      const int h = ht * 16 + lc * 4 + e;
      dfbv[ht][e] = (h < 30) ? dfbg[h] : 0.f;
    }

  const float* Db = Dg + (size_t)b * (30 * 30 * 56);
  uint2* dhb = dhg + (size_t)b * (30 * 30 * 8);
  const f4 z4 = {0.f, 0.f, 0.f, 0.f};

  const int tiles = (nn + 15) >> 4;
  for (int t = w; t < tiles; t += 4) {
    const int p_raw = t * 16 + lr;
    const int p = min(p_raw, nn - 1);
    const int i = (int)(((unsigned)p * inv) >> 16);
    const int j = p - i * n;
    const int row = i * 30 + j;
    const float* Dp = Db + (size_t)row * 56;

    float4 q0 = *reinterpret_cast<const float4*>(Dp + lc * 8);
    float4 q1 = *reinterpret_cast<const float4*>(Dp + lc * 8 + 4);
    float4 q2 = {0.f, 0.f, 0.f, 0.f}, q3 = {0.f, 0.f, 0.f, 0.f};
    if (lc < 3) {
      q2 = *reinterpret_cast<const float4*>(Dp + 32 + lc * 8);
      q3 = *reinterpret_cast<const float4*>(Dp + 32 + lc * 8 + 4);
    }
    bh8 B0 = mk_bh8(cvtpk(q0.x, q0.y), cvtpk(q0.z, q0.w),
                    cvtpk(q1.x, q1.y), cvtpk(q1.z, q1.w));
    bh8 B1 = mk_bh8(cvtpk(q2.x, q2.y), cvtpk(q2.z, q2.w),
                    cvtpk(q3.x, q3.y), cvtpk(q3.z, q3.w));

    f4 a0 = z4, a1 = z4;
    a0 = MFMA_BF16(Al[0][0], B0, a0, 0, 0, 0);
    a0 = MFMA_BF16(Ah[0][0], B0, a0, 0, 0, 0);
    a0 = MFMA_BF16(Al[0][1], B1, a0, 0, 0, 0);
    a0 = MFMA_BF16(Ah[0][1], B1, a0, 0, 0, 0);
    a1 = MFMA_BF16(Al[1][0], B0, a1, 0, 0, 0);
    a1 = MFMA_BF16(Ah[1][0], B0, a1, 0, 0, 0);
    a1 = MFMA_BF16(Al[1][1], B1, a1, 0, 0, 0);
    a1 = MFMA_BF16(Ah[1][1], B1, a1, 0, 0, 0);

    if (p_raw < nn) {
      uint2 s0, s1;
      s0.x = cvtpk(a0[0] + dfbv[0][0], a0[1] + dfbv[0][1]);
      s0.y = cvtpk(a0[2] + dfbv[0][2], a0[3] + dfbv[0][3]);
      s1.x = cvtpk(a1[0] + dfbv[1][0], a1[1] + dfbv[1][1]);
      s1.y = cvtpk(a1[2] + dfbv[1][2], a1[3] + dfbv[1][3]);
      dhb[row * 8 + 0 * 4 + lc] = s0;
      dhb[row * 8 + 1 * 4 + lc] = s1;
    }
  }
}

// ---------------------------------------------------------------------------
// Phase B (exact R12 body; molecule = perm[blockIdx.x] for LPT order).
// ---------------------------------------------------------------------------
__global__ __launch_bounds__(128, 3) void mdtnn_phB5(
    const int* __restrict__ Zg, const int* __restrict__ sizesg,
    const float* __restrict__ embg, const float* __restrict__ cfwg,
    const float* __restrict__ cfbg, const float* __restrict__ fcwg,
    const float* __restrict__ w1g, const float* __restrict__ b1g,
    const float* __restrict__ w2g, const float* __restrict__ b2g,
    const unsigned* __restrict__ dhg, float* __restrict__ outg,
    const int* __restrict__ perm)
{
  const int tid = threadIdx.x;
  const int wid = tid >> 6, l = tid & 63;
  const int lr = l & 15, lc = l >> 4;
  const int bm = perm[blockIdx.x];

  __shared__ __align__(16) float buf[2][32][36];   // per-wave bufs
  __shared__ __align__(16) float w1_s[32][16];
  __shared__ float b1_s[16], w2_s[16], wsum[2];

  for (int t = tid; t < 512; t += 128) {
    int k = t >> 4, c = t & 15;
    w1_s[k][c] = (k < 30 && c < 15) ? w1g[k * 15 + c] : 0.f;
  }
  if (tid < 16) {
    b1_s[tid] = (tid < 15) ? b1g[tid] : 0.f;
    w2_s[tid] = (tid < 15) ? w2g[tid] : 0.f;
  }

  const int n = sizesg[bm];
  float (*mybuf)[36] = buf[wid];

  float fcwF0[8], fcwF1[8];
  bh8 cfwB0h, cfwB0l, cfwB1h, cfwB1l;
  #pragma unroll
  for (int e = 0; e < 8; ++e) {
    const int kk = lc * 8 + e;
    const int c1 = lr + 16;
    fcwF0[e] = (kk < 30) ? fcwg[kk * 30 + lr] : 0.f;
    fcwF1[e] = (kk < 30 && c1 < 30) ? fcwg[kk * 30 + c1] : 0.f;
    float g0 = (kk < 30) ? cfwg[kk * 30 + lr] : 0.f;
    float g1 = (kk < 30 && c1 < 30) ? cfwg[kk * 30 + c1] : 0.f;
    float hf;
    cfwB0h[e] = bf16hi(g0, &hf);
    cfwB0l[e] = bf16s(g0 - hf);
    cfwB1h[e] = bf16hi(g1, &hf);
    cfwB1l[e] = bf16s(g1 - hf);
  }
  const float cfb0 = cfbg[lr];
  const float cfb1 = (lr + 16 < 30) ? cfbg[lr + 16] : 0.f;

  // C in registers, D-frag layout (duplicated in both waves)
  f4 C00, C01, C10, C11;
  #pragma unroll
  for (int e = 0; e < 4; ++e) {
    const int r0 = lc * 4 + e;
    const int r1 = 16 + lc * 4 + e;
    const int z0 = Zg[bm * 30 + r0];
    C00[e] = embg[z0 * 30 + lr];
    C01[e] = (lr + 16 < 30) ? embg[z0 * 30 + lr + 16] : 0.f;
    if (r1 < 30) {
      const int z1 = Zg[bm * 30 + r1];
      C10[e] = embg[z1 * 30 + lr];
      C11[e] = (lr + 16 < 30) ? embg[z1 * 30 + lr + 16] : 0.f;
    } else {
      C10[e] = 0.f;
      C11[e] = 0.f;
    }
  }

  const unsigned* dhb = dhg + (size_t)bm * 14400;   // dwords
  const int n0 = (n + 1) >> 1;
  const int ibeg = wid ? n0 : 0;
  const int iend = wid ? n : n0;
  const bool j0ok = (lr < n), j1ok = (lr + 16 < n);
  const f4 z4 = {0.f, 0.f, 0.f, 0.f};

  __syncthreads();   // staging done; bufs free

  for (int it = 0; it < 3; ++it) {
    // prefetch first dh of this wave's range (overlaps X1 compute)
    uint4 a0c = {0, 0, 0, 0}, a1c = {0, 0, 0, 0};
    if (ibeg < iend) {
      const unsigned* p = dhb + (size_t)ibeg * 480;
      if (j0ok) a0c = *reinterpret_cast<const uint4*>(p + lr * 16 + lc * 4);
      if (j1ok) a1c = *reinterpret_cast<const uint4*>(p + lr * 16 + 256 + lc * 4);
    }

    // ---- X1 (redundant per wave): spill C, A-frags, 12 MFMAs, write X1 ----
    #pragma unroll
    for (int e = 0; e < 4; ++e) {
      mybuf[lc * 4 + e][lr]           = C00[e];
      mybuf[lc * 4 + e][lr + 16]      = C01[e];
      mybuf[16 + lc * 4 + e][lr]      = C10[e];
      mybuf[16 + lc * 4 + e][lr + 16] = C11[e];
    }
    float cv0[8], cv1[8];
    *reinterpret_cast<float4*>(&cv0[0]) = *reinterpret_cast<const float4*>(&mybuf[lr][lc * 8]);
    *reinterpret_cast<float4*>(&cv0[4]) = *reinterpret_cast<const float4*>(&mybuf[lr][lc * 8 + 4]);
    *reinterpret_cast<float4*>(&cv1[0]) = *reinterpret_cast<const float4*>(&mybuf[16 + lr][lc * 8]);
    *reinterpret_cast<float4*>(&cv1[4]) = *reinterpret_cast<const float4*>(&mybuf[16 + lr][lc * 8 + 4]);

    unsigned h_[4], lo_[4];
    #pragma unroll
    for (int q = 0; q < 4; ++q) {
      unsigned hq = cvtpk(cv0[2 * q], cv0[2 * q + 1]);
      float f0 = __uint_as_float(hq << 16);
      float f1 = __uint_as_float(hq & 0xffff0000u);
      h_[q] = hq;
      lo_[q] = cvtpk(cv0[2 * q] - f0, cv0[2 * q + 1] - f1);
    }
    bh8 Ch0 = mk_bh8(h_[0], h_[1], h_[2], h_[3]);
    bh8 Cl0 = mk_bh8(lo_[0], lo_[1], lo_[2], lo_[3]);
    #pragma unroll
    for (int q = 0; q < 4; ++q) {
      unsigned hq = cvtpk(cv1[2 * q], cv1[2 * q + 1]);
      float f0 = __uint_as_float(hq << 16);
      float f1 = __uint_as_float(hq & 0xffff0000u);
      h_[q] = hq;
      lo_[q] = cvtpk(cv1[2 * q] - f0, cv1[2 * q + 1] - f1);
    }
    bh8 Ch1 = mk_bh8(h_[0], h_[1], h_[2], h_[3]);
    bh8 Cl1 = mk_bh8(lo_[0], lo_[1], lo_[2], lo_[3]);

    f4 d00 = MFMA_BF16(Ch0, cfwB0l, z4, 0, 0, 0);
    d00 = MFMA_BF16(Cl0, cfwB0h, d00, 0, 0, 0);
    d00 = MFMA_BF16(Ch0, cfwB0h, d00, 0, 0, 0);
    f4 d01 = MFMA_BF16(Ch0, cfwB1l, z4, 0, 0, 0);
    d01 = MFMA_BF16(Cl0, cfwB1h, d01, 0, 0, 0);
    d01 = MFMA_BF16(Ch0, cfwB1h, d01, 0, 0, 0);
    f4 d10 = MFMA_BF16(Ch1, cfwB0l, z4, 0, 0, 0);
    d10 = MFMA_BF16(Cl1, cfwB0h, d10, 0, 0, 0);
    d10 = MFMA_BF16(Ch1, cfwB0h, d10, 0, 0, 0);
    f4 d11 = MFMA_BF16(Ch1, cfwB1l, z4, 0, 0, 0);
    d11 = MFMA_BF16(Cl1, cfwB1h, d11, 0, 0, 0);
    d11 = MFMA_BF16(Ch1, cfwB1h, d11, 0, 0, 0);
    #pragma unroll
    for (int e = 0; e < 4; ++e) {
      mybuf[lc * 4 + e][lr]           = d00[e] + cfb0;
      mybuf[lc * 4 + e][lr + 16]      = d01[e] + cfb1;
      mybuf[16 + lc * 4 + e][lr]      = d10[e] + cfb0;
      mybuf[16 + lc * 4 + e][lr + 16] = d11[e] + cfb1;
    }

    // ---- i-loop over this wave's half (wave-private, one-ahead prefetch) ----
    f4 i00 = z4, i01 = z4, i10 = z4, i11 = z4;
    for (int i = ibeg; i < iend; ++i) {
      uint4 a0n = {0, 0, 0, 0}, a1n = {0, 0, 0, 0};
      if (i + 1 < iend) {
        const unsigned* p = dhb + (size_t)(i + 1) * 480;
        if (j0ok) a0n = *reinterpret_cast<const uint4*>(p + lr * 16 + lc * 4);
        if (j1ok) a1n = *reinterpret_cast<const uint4*>(p + lr * 16 + 256 + lc * 4);
      }
      float4 xA = *reinterpret_cast<const float4*>(&mybuf[i][lc * 8]);
      float4 xB = *reinterpret_cast<const float4*>(&mybuf[i][lc * 8 + 4]);
      float xv[8] = {xA.x, xA.y, xA.z, xA.w, xB.x, xB.y, xB.z, xB.w};
      bh8 W0 = mk_bh8(cvtpk(xv[0] * fcwF0[0], xv[1] * fcwF0[1]),
                      cvtpk(xv[2] * fcwF0[2], xv[3] * fcwF0[3]),
                      cvtpk(xv[4] * fcwF0[4], xv[5] * fcwF0[5]),
                      cvtpk(xv[6] * fcwF0[6], xv[7] * fcwF0[7]));
      bh8 W1 = mk_bh8(cvtpk(xv[0] * fcwF1[0], xv[1] * fcwF1[1]),
                      cvtpk(xv[2] * fcwF1[2], xv[3] * fcwF1[3]),
                      cvtpk(xv[4] * fcwF1[4], xv[5] * fcwF1[5]),
                      cvtpk(xv[6] * fcwF1[6], xv[7] * fcwF1[7]));
      const bh8 A0 = __builtin_bit_cast(bh8, a0c);
      const bh8 A1 = __builtin_bit_cast(bh8, a1c);
      f4 g;
      g = MFMA_BF16(A0, W0, z4, 0, 0, 0);
      #pragma unroll
      for (int e = 0; e < 4; ++e) i00[e] += fast_tanh(g[e]);
      g = MFMA_BF16(A0, W1, z4, 0, 0, 0);
      #pragma unroll
      for (int e = 0; e < 4; ++e) i01[e] += fast_tanh(g[e]);
      g = MFMA_BF16(A1, W0, z4, 0, 0, 0);
      #pragma unroll
      for (int e = 0; e < 4; ++e) i10[e] += fast_tanh(g[e]);
      g = MFMA_BF16(A1, W1, z4, 0, 0, 0);
      #pragma unroll
      for (int e = 0; e < 4; ++e) i11[e] += fast_tanh(g[e]);
      a0c = a0n;
      a1c = a1n;
    }

    // ---- inc exchange: write own, barrier, read both in fixed order ----
    #pragma unroll
    for (int e = 0; e < 4; ++e) {
      mybuf[lc * 4 + e][lr]           = i00[e];
      mybuf[lc * 4 + e][lr + 16]      = i01[e];
      mybuf[16 + lc * 4 + e][lr]      = i10[e];
      mybuf[16 + lc * 4 + e][lr + 16] = i11[e];
    }
    __syncthreads();
    #pragma unroll
    for (int e = 0; e < 4; ++e) {
      C00[e] += buf[0][lc * 4 + e][lr];
      C00[e] += buf[1][lc * 4 + e][lr];
      C01[e] += buf[0][lc * 4 + e][lr + 16];
      C01[e] += buf[1][lc * 4 + e][lr + 16];
      C10[e] += buf[0][16 + lc * 4 + e][lr];
      C10[e] += buf[1][16 + lc * 4 + e][lr];
      C11[e] += buf[0][16 + lc * 4 + e][lr + 16];
      C11[e] += buf[1][16 + lc * 4 + e][lr + 16];
    }
    __syncthreads();   // protect bufs before next iteration's X1 write
  }

  // ---- head: spill (identical) C to own buf; waves split the rows ----
  #pragma unroll
  for (int e = 0; e < 4; ++e) {
    mybuf[lc * 4 + e][lr]           = C00[e];
    mybuf[lc * 4 + e][lr + 16]      = C01[e];
    mybuf[16 + lc * 4 + e][lr]      = C10[e];
    mybuf[16 + lc * 4 + e][lr + 16] = C11[e];
  }
  float esum = 0.f;
  for (int t = l + wid * 64; t < n * 16; t += 128) {
    int j = t >> 4, c = t & 15;
    if (c < 15) {
      float a = b1_s[c];
      #pragma unroll
      for (int kc = 0; kc < 8; ++kc) {
        float4 c4 = *reinterpret_cast<const float4*>(&mybuf[j][kc * 4]);
        a = fmaf(c4.x, w1_s[kc * 4 + 0][c], a);
        a = fmaf(c4.y, w1_s[kc * 4 + 1][c], a);
        a = fmaf(c4.z, w1_s[kc * 4 + 2][c], a);
        a = fmaf(c4.w, w1_s[kc * 4 + 3][c], a);
      }
      esum += fast_tanh(a) * w2_s[c];
    }
  }
  #pragma unroll
  for (int off = 32; off; off >>= 1) esum += __shfl_down(esum, off);
  if (l == 0) wsum[wid] = esum;
  __syncthreads();
  if (tid == 0) outg[bm] = wsum[0] + wsum[1] + (float)n * b2g[0];
}

extern "C" void kernel_launch(void* const* d_in, const int* in_sizes, int n_in,
                              void* d_out, int out_size, void* d_ws, size_t ws_size,
                              hipStream_t stream) {
  (void)in_sizes; (void)n_in; (void)ws_size;
  const int*   Z   = (const int*)d_in[0];
  const float* D   = (const float*)d_in[1];
  const int*   sz  = (const int*)d_in[2];
  const float* emb = (const float*)d_in[3];
  const float* dfw = (const float*)d_in[4];
  const float* dfb = (const float*)d_in[5];
  const float* cfw = (const float*)d_in[6];
  const float* cfb = (const float*)d_in[7];
  const float* fcw = (const float*)d_in[8];
  const float* w1  = (const float*)d_in[9];
  const float* b1  = (const float*)d_in[10];
  const float* w2  = (const float*)d_in[11];
  const float* b2  = (const float*)d_in[12];
  float* out = (float*)d_out;
  const int B = out_size;  // 2048

  const size_t DHB = (size_t)B * 30 * 30 * 64;   // 118 MB d_hat
  int* perm = (int*)((char*)d_ws + DHB);

  mdtnn_rank<<<dim3((B + 255) / 256), dim3(256), 0, stream>>>(sz, B, perm);
  mdtnn_phA_mfma<<<dim3(B), dim3(256), 0, stream>>>(D, sz, dfw, dfb,
                                                    (uint2*)d_ws, perm);
  mdtnn_phB5<<<dim3(B), dim3(128), 0, stream>>>(Z, sz, emb, cfw, cfb, fcw,
                                                w1, b1, w2, b2,
                                                (const unsigned*)d_ws, out, perm);
}

// Round 18
// 107.691 us; speedup vs baseline: 4.3089x; 1.3088x over previous
//
#include <hip/hip_runtime.h>
#include <hip/hip_bf16.h>

typedef __attribute__((ext_vector_type(8))) short bh8;   // 8 x bf16 (4 VGPR) MFMA A/B frag
typedef __attribute__((ext_vector_type(4))) float f4;    // 4 x f32 MFMA C/D frag

#define MFMA_BF16 __builtin_amdgcn_mfma_f32_16x16x32_bf16

// packed f32x2 -> bf16x2 (RNE), dst.lo = a, dst.hi = b  [T12 recipe]
__device__ __forceinline__ unsigned cvtpk(float a, float b) {
  unsigned r;
  asm("v_cvt_pk_bf16_f32 %0, %1, %2" : "=v"(r) : "v"(a), "v"(b));
  return r;
}
__device__ __forceinline__ bh8 mk_bh8(unsigned a, unsigned b, unsigned c, unsigned d) {
  uint4 u;
  u.x = a; u.y = b; u.z = c; u.w = d;
  return __builtin_bit_cast(bh8, u);
}

// tanh(x) = 1 - 2/(e^{2x}+1); clamp-free. 2 VALU + 2 trans.
__device__ __forceinline__ float fast_tanh(float x) {
  float e = __builtin_amdgcn_exp2f(x * 2.885390081777927f);
  return fmaf(-2.f, __builtin_amdgcn_rcpf(e + 1.f), 1.f);
}

// scalar RNE casts (cold paths only)
__device__ __forceinline__ short bf16hi(float f, float* hf) {
  __hip_bfloat16 h = __float2bfloat16(f);
  *hf = __bfloat162float(h);
  short s;
  __builtin_memcpy(&s, &h, 2);
  return s;
}
__device__ __forceinline__ short bf16s(float f) {
  __hip_bfloat16 h = __float2bfloat16(f);
  short s;
  __builtin_memcpy(&s, &h, 2);
  return s;
}

// d_hat layout: [b][i(30)][j(30)][h(32, bf16)] -> 64 B per (i,j) pair.

// ---------------------------------------------------------------------------
// Phase A (MFMA): d_hat = D@df_w+df_b -> global bf16. Hot converts via cvt_pk.
// ---------------------------------------------------------------------------
__global__ __launch_bounds__(256, 4) void mdtnn_phA_mfma(
    const float* __restrict__ Dg, const int* __restrict__ sizesg,
    const float* __restrict__ dfwg, const float* __restrict__ dfbg,
    uint2* __restrict__ dhg)
{
  const int b = blockIdx.x, tid = threadIdx.x;
  const int w = tid >> 6, l = tid & 63;
  const int lr = l & 15, lc = l >> 4;
  const int n = sizesg[b];
  const int nn = n * n;
  const unsigned inv = (65536u + (unsigned)n - 1) / (unsigned)n;  // exact p/n for p<1024

  bh8 Ah[2][2], Al[2][2];
  #pragma unroll
  for (int ht = 0; ht < 2; ++ht) {
    const int h = ht * 16 + lr;
    #pragma unroll
    for (int kc = 0; kc < 2; ++kc) {
      #pragma unroll
      for (int e = 0; e < 8; ++e) {
        const int g = kc * 32 + lc * 8 + e;
        float v = (g < 56 && h < 30) ? dfwg[g * 30 + h] : 0.f;
        float hf;
        Ah[ht][kc][e] = bf16hi(v, &hf);
        Al[ht][kc][e] = bf16s(v - hf);
      }
    }
  }
  float dfbv[2][4];
  #pragma unroll
  for (int ht = 0; ht < 2; ++ht)
    #pragma unroll
    for (int e = 0; e < 4; ++e) {
      const int h = ht * 16 + lc * 4 + e;
      dfbv[ht][e] = (h < 30) ? dfbg[h] : 0.f;
    }

  const float* Db = Dg + (size_t)b * (30 * 30 * 56);
  uint2* dhb = dhg + (size_t)b * (30 * 30 * 8);
  const f4 z4 = {0.f, 0.f, 0.f, 0.f};

  const int tiles = (nn + 15) >> 4;
  for (int t = w; t < tiles; t += 4) {
    const int p_raw = t * 16 + lr;
    const int p = min(p_raw, nn - 1);
    const int i = (int)(((unsigned)p * inv) >> 16);
    const int j = p - i * n;
    const int row = i * 30 + j;
    const float* Dp = Db + (size_t)row * 56;

    float4 q0 = *reinterpret_cast<const float4*>(Dp + lc * 8);
    float4 q1 = *reinterpret_cast<const float4*>(Dp + lc * 8 + 4);
    float4 q2 = {0.f, 0.f, 0.f, 0.f}, q3 = {0.f, 0.f, 0.f, 0.f};
    if (lc < 3) {
      q2 = *reinterpret_cast<const float4*>(Dp + 32 + lc * 8);
      q3 = *reinterpret_cast<const float4*>(Dp + 32 + lc * 8 + 4);
    }
    bh8 B0 = mk_bh8(cvtpk(q0.x, q0.y), cvtpk(q0.z, q0.w),
                    cvtpk(q1.x, q1.y), cvtpk(q1.z, q1.w));
    bh8 B1 = mk_bh8(cvtpk(q2.x, q2.y), cvtpk(q2.z, q2.w),
                    cvtpk(q3.x, q3.y), cvtpk(q3.z, q3.w));

    f4 a0 = z4, a1 = z4;
    a0 = MFMA_BF16(Al[0][0], B0, a0, 0, 0, 0);
    a0 = MFMA_BF16(Ah[0][0], B0, a0, 0, 0, 0);
    a0 = MFMA_BF16(Al[0][1], B1, a0, 0, 0, 0);
    a0 = MFMA_BF16(Ah[0][1], B1, a0, 0, 0, 0);
    a1 = MFMA_BF16(Al[1][0], B0, a1, 0, 0, 0);
    a1 = MFMA_BF16(Ah[1][0], B0, a1, 0, 0, 0);
    a1 = MFMA_BF16(Al[1][1], B1, a1, 0, 0, 0);
    a1 = MFMA_BF16(Ah[1][1], B1, a1, 0, 0, 0);

    if (p_raw < nn) {
      uint2 s0, s1;
      s0.x = cvtpk(a0[0] + dfbv[0][0], a0[1] + dfbv[0][1]);
      s0.y = cvtpk(a0[2] + dfbv[0][2], a0[3] + dfbv[0][3]);
      s1.x = cvtpk(a1[0] + dfbv[1][0], a1[1] + dfbv[1][1]);
      s1.y = cvtpk(a1[2] + dfbv[1][2], a1[3] + dfbv[1][3]);
      dhb[row * 8 + 0 * 4 + lc] = s0;
      dhb[row * 8 + 1 * 4 + lc] = s1;
    }
  }
}

// ---------------------------------------------------------------------------
// Phase B v5: one molecule per 128-thr block, 2 waves, duplicated C in regs,
// wave-private X1 bufs, i-range halved, 2 barriers/iter, zero atomics.
// W' and C-splits via packed cvt.
// ---------------------------------------------------------------------------
__global__ __launch_bounds__(128, 3) void mdtnn_phB5(
    const int* __restrict__ Zg, const int* __restrict__ sizesg,
    const float* __restrict__ embg, const float* __restrict__ cfwg,
    const float* __restrict__ cfbg, const float* __restrict__ fcwg,
    const float* __restrict__ w1g, const float* __restrict__ b1g,
    const float* __restrict__ w2g, const float* __restrict__ b2g,
    const unsigned* __restrict__ dhg, float* __restrict__ outg)
{
  const int tid = threadIdx.x;
  const int wid = tid >> 6, l = tid & 63;
  const int lr = l & 15, lc = l >> 4;
  const int bm = blockIdx.x;

  __shared__ __align__(16) float buf[2][32][36];   // per-wave bufs
  __shared__ __align__(16) float w1_s[32][16];
  __shared__ float b1_s[16], w2_s[16], wsum[2];

  for (int t = tid; t < 512; t += 128) {
    int k = t >> 4, c = t & 15;
    w1_s[k][c] = (k < 30 && c < 15) ? w1g[k * 15 + c] : 0.f;
  }
  if (tid < 16) {
    b1_s[tid] = (tid < 15) ? b1g[tid] : 0.f;
    w2_s[tid] = (tid < 15) ? w2g[tid] : 0.f;
  }

  const int n = sizesg[bm];
  float (*mybuf)[36] = buf[wid];

  float fcwF0[8], fcwF1[8];
  bh8 cfwB0h, cfwB0l, cfwB1h, cfwB1l;
  #pragma unroll
  for (int e = 0; e < 8; ++e) {
    const int kk = lc * 8 + e;
    const int c1 = lr + 16;
    fcwF0[e] = (kk < 30) ? fcwg[kk * 30 + lr] : 0.f;
    fcwF1[e] = (kk < 30 && c1 < 30) ? fcwg[kk * 30 + c1] : 0.f;
    float g0 = (kk < 30) ? cfwg[kk * 30 + lr] : 0.f;
    float g1 = (kk < 30 && c1 < 30) ? cfwg[kk * 30 + c1] : 0.f;
    float hf;
    cfwB0h[e] = bf16hi(g0, &hf);
    cfwB0l[e] = bf16s(g0 - hf);
    cfwB1h[e] = bf16hi(g1, &hf);
    cfwB1l[e] = bf16s(g1 - hf);
  }
  const float cfb0 = cfbg[lr];
  const float cfb1 = (lr + 16 < 30) ? cfbg[lr + 16] : 0.f;

  // C in registers, D-frag layout (duplicated in both waves)
  f4 C00, C01, C10, C11;
  #pragma unroll
  for (int e = 0; e < 4; ++e) {
    const int r0 = lc * 4 + e;
    const int r1 = 16 + lc * 4 + e;
    const int z0 = Zg[bm * 30 + r0];
    C00[e] = embg[z0 * 30 + lr];
    C01[e] = (lr + 16 < 30) ? embg[z0 * 30 + lr + 16] : 0.f;
    if (r1 < 30) {
      const int z1 = Zg[bm * 30 + r1];
      C10[e] = embg[z1 * 30 + lr];
      C11[e] = (lr + 16 < 30) ? embg[z1 * 30 + lr + 16] : 0.f;
    } else {
      C10[e] = 0.f;
      C11[e] = 0.f;
    }
  }

  const unsigned* dhb = dhg + (size_t)bm * 14400;   // dwords
  const int n0 = (n + 1) >> 1;
  const int ibeg = wid ? n0 : 0;
  const int iend = wid ? n : n0;
  const bool j0ok = (lr < n), j1ok = (lr + 16 < n);
  const f4 z4 = {0.f, 0.f, 0.f, 0.f};

  __syncthreads();   // staging done; bufs free

  for (int it = 0; it < 3; ++it) {
    // prefetch first dh of this wave's range (overlaps X1 compute)
    uint4 a0c = {0, 0, 0, 0}, a1c = {0, 0, 0, 0};
    if (ibeg < iend) {
      const unsigned* p = dhb + (size_t)ibeg * 480;
      if (j0ok) a0c = *reinterpret_cast<const uint4*>(p + lr * 16 + lc * 4);
      if (j1ok) a1c = *reinterpret_cast<const uint4*>(p + lr * 16 + 256 + lc * 4);
    }

    // ---- X1 (redundant per wave): spill C, A-frags, 12 MFMAs, write X1 ----
    #pragma unroll
    for (int e = 0; e < 4; ++e) {
      mybuf[lc * 4 + e][lr]           = C00[e];
      mybuf[lc * 4 + e][lr + 16]      = C01[e];
      mybuf[16 + lc * 4 + e][lr]      = C10[e];
      mybuf[16 + lc * 4 + e][lr + 16] = C11[e];
    }
    float cv0[8], cv1[8];
    *reinterpret_cast<float4*>(&cv0[0]) = *reinterpret_cast<const float4*>(&mybuf[lr][lc * 8]);
    *reinterpret_cast<float4*>(&cv0[4]) = *reinterpret_cast<const float4*>(&mybuf[lr][lc * 8 + 4]);
    *reinterpret_cast<float4*>(&cv1[0]) = *reinterpret_cast<const float4*>(&mybuf[16 + lr][lc * 8]);
    *reinterpret_cast<float4*>(&cv1[4]) = *reinterpret_cast<const float4*>(&mybuf[16 + lr][lc * 8 + 4]);

    // packed hi/lo split: hi = RNE(cv) (pk), lo = RNE(cv - f32(hi)) (pk)
    unsigned h_[4], lo_[4];
    #pragma unroll
    for (int q = 0; q < 4; ++q) {
      unsigned hq = cvtpk(cv0[2 * q], cv0[2 * q + 1]);
      float f0 = __uint_as_float(hq << 16);
      float f1 = __uint_as_float(hq & 0xffff0000u);
      h_[q] = hq;
      lo_[q] = cvtpk(cv0[2 * q] - f0, cv0[2 * q + 1] - f1);
    }
    bh8 Ch0 = mk_bh8(h_[0], h_[1], h_[2], h_[3]);
    bh8 Cl0 = mk_bh8(lo_[0], lo_[1], lo_[2], lo_[3]);
    #pragma unroll
    for (int q = 0; q < 4; ++q) {
      unsigned hq = cvtpk(cv1[2 * q], cv1[2 * q + 1]);
      float f0 = __uint_as_float(hq << 16);
      float f1 = __uint_as_float(hq & 0xffff0000u);
      h_[q] = hq;
      lo_[q] = cvtpk(cv1[2 * q] - f0, cv1[2 * q + 1] - f1);
    }
    bh8 Ch1 = mk_bh8(h_[0], h_[1], h_[2], h_[3]);
    bh8 Cl1 = mk_bh8(lo_[0], lo_[1], lo_[2], lo_[3]);

    f4 d00 = MFMA_BF16(Ch0, cfwB0l, z4, 0, 0, 0);
    d00 = MFMA_BF16(Cl0, cfwB0h, d00, 0, 0, 0);
    d00 = MFMA_BF16(Ch0, cfwB0h, d00, 0, 0, 0);
    f4 d01 = MFMA_BF16(Ch0, cfwB1l, z4, 0, 0, 0);
    d01 = MFMA_BF16(Cl0, cfwB1h, d01, 0, 0, 0);
    d01 = MFMA_BF16(Ch0, cfwB1h, d01, 0, 0, 0);
    f4 d10 = MFMA_BF16(Ch1, cfwB0l, z4, 0, 0, 0);
    d10 = MFMA_BF16(Cl1, cfwB0h, d10, 0, 0, 0);
    d10 = MFMA_BF16(Ch1, cfwB0h, d10, 0, 0, 0);
    f4 d11 = MFMA_BF16(Ch1, cfwB1l, z4, 0, 0, 0);
    d11 = MFMA_BF16(Cl1, cfwB1h, d11, 0, 0, 0);
    d11 = MFMA_BF16(Ch1, cfwB1h, d11, 0, 0, 0);
    #pragma unroll
    for (int e = 0; e < 4; ++e) {
      mybuf[lc * 4 + e][lr]           = d00[e] + cfb0;
      mybuf[lc * 4 + e][lr + 16]      = d01[e] + cfb1;
      mybuf[16 + lc * 4 + e][lr]      = d10[e] + cfb0;
      mybuf[16 + lc * 4 + e][lr + 16] = d11[e] + cfb1;
    }

    // ---- i-loop over this wave's half (wave-private, one-ahead prefetch) ----
    f4 i00 = z4, i01 = z4, i10 = z4, i11 = z4;
    for (int i = ibeg; i < iend; ++i) {
      uint4 a0n = {0, 0, 0, 0}, a1n = {0, 0, 0, 0};
      if (i + 1 < iend) {
        const unsigned* p = dhb + (size_t)(i + 1) * 480;
        if (j0ok) a0n = *reinterpret_cast<const uint4*>(p + lr * 16 + lc * 4);
        if (j1ok) a1n = *reinterpret_cast<const uint4*>(p + lr * 16 + 256 + lc * 4);
      }
      float4 xA = *reinterpret_cast<const float4*>(&mybuf[i][lc * 8]);
      float4 xB = *reinterpret_cast<const float4*>(&mybuf[i][lc * 8 + 4]);
      float xv[8] = {xA.x, xA.y, xA.z, xA.w, xB.x, xB.y, xB.z, xB.w};
      bh8 W0 = mk_bh8(cvtpk(xv[0] * fcwF0[0], xv[1] * fcwF0[1]),
                      cvtpk(xv[2] * fcwF0[2], xv[3] * fcwF0[3]),
                      cvtpk(xv[4] * fcwF0[4], xv[5] * fcwF0[5]),
                      cvtpk(xv[6] * fcwF0[6], xv[7] * fcwF0[7]));
      bh8 W1 = mk_bh8(cvtpk(xv[0] * fcwF1[0], xv[1] * fcwF1[1]),
                      cvtpk(xv[2] * fcwF1[2], xv[3] * fcwF1[3]),
                      cvtpk(xv[4] * fcwF1[4], xv[5] * fcwF1[5]),
                      cvtpk(xv[6] * fcwF1[6], xv[7] * fcwF1[7]));
      const bh8 A0 = __builtin_bit_cast(bh8, a0c);
      const bh8 A1 = __builtin_bit_cast(bh8, a1c);
      f4 g;
      g = MFMA_BF16(A0, W0, z4, 0, 0, 0);
      #pragma unroll
      for (int e = 0; e < 4; ++e) i00[e] += fast_tanh(g[e]);
      g = MFMA_BF16(A0, W1, z4, 0, 0, 0);
      #pragma unroll
      for (int e = 0; e < 4; ++e) i01[e] += fast_tanh(g[e]);
      g = MFMA_BF16(A1, W0, z4, 0, 0, 0);
      #pragma unroll
      for (int e = 0; e < 4; ++e) i10[e] += fast_tanh(g[e]);
      g = MFMA_BF16(A1, W1, z4, 0, 0, 0);
      #pragma unroll
      for (int e = 0; e < 4; ++e) i11[e] += fast_tanh(g[e]);
      a0c = a0n;
      a1c = a1n;
    }

    // ---- inc exchange: write own, barrier, read both in fixed order ----
    #pragma unroll
    for (int e = 0; e < 4; ++e) {
      mybuf[lc * 4 + e][lr]           = i00[e];
      mybuf[lc * 4 + e][lr + 16]      = i01[e];
      mybuf[16 + lc * 4 + e][lr]      = i10[e];
      mybuf[16 + lc * 4 + e][lr + 16] = i11[e];
    }
    __syncthreads();
    #pragma unroll
    for (int e = 0; e < 4; ++e) {
      C00[e] += buf[0][lc * 4 + e][lr];
      C00[e] += buf[1][lc * 4 + e][lr];
      C01[e] += buf[0][lc * 4 + e][lr + 16];
      C01[e] += buf[1][lc * 4 + e][lr + 16];
      C10[e] += buf[0][16 + lc * 4 + e][lr];
      C10[e] += buf[1][16 + lc * 4 + e][lr];
      C11[e] += buf[0][16 + lc * 4 + e][lr + 16];
      C11[e] += buf[1][16 + lc * 4 + e][lr + 16];
    }
    __syncthreads();   // protect bufs before next iteration's X1 write
  }

  // ---- head: each wave spills its (identical) C to own buf; split rows ----
  #pragma unroll
  for (int e = 0; e < 4; ++e) {
    mybuf[lc * 4 + e][lr]           = C00[e];
    mybuf[lc * 4 + e][lr + 16]      = C01[e];
    mybuf[16 + lc * 4 + e][lr]      = C10[e];
    mybuf[16 + lc * 4 + e][lr + 16] = C11[e];
  }
  float esum = 0.f;
  for (int t = l + wid * 64; t < n * 16; t += 128) {
    int j = t >> 4, c = t & 15;
    if (c < 15) {
      float a = b1_s[c];
      #pragma unroll
      for (int kc = 0; kc < 8; ++kc) {
        float4 c4 = *reinterpret_cast<const float4*>(&mybuf[j][kc * 4]);
        a = fmaf(c4.x, w1_s[kc * 4 + 0][c], a);
        a = fmaf(c4.y, w1_s[kc * 4 + 1][c], a);
        a = fmaf(c4.z, w1_s[kc * 4 + 2][c], a);
        a = fmaf(c4.w, w1_s[kc * 4 + 3][c], a);
      }
      esum += fast_tanh(a) * w2_s[c];
    }
  }
  #pragma unroll
  for (int off = 32; off; off >>= 1) esum += __shfl_down(esum, off);
  if (l == 0) wsum[wid] = esum;
  __syncthreads();
  if (tid == 0) outg[bm] = wsum[0] + wsum[1] + (float)n * b2g[0];
}

extern "C" void kernel_launch(void* const* d_in, const int* in_sizes, int n_in,
                              void* d_out, int out_size, void* d_ws, size_t ws_size,
                              hipStream_t stream) {
  (void)in_sizes; (void)n_in; (void)ws_size;
  const int*   Z   = (const int*)d_in[0];
  const float* D   = (const float*)d_in[1];
  const int*   sz  = (const int*)d_in[2];
  const float* emb = (const float*)d_in[3];
  const float* dfw = (const float*)d_in[4];
  const float* dfb = (const float*)d_in[5];
  const float* cfw = (const float*)d_in[6];
  const float* cfb = (const float*)d_in[7];
  const float* fcw = (const float*)d_in[8];
  const float* w1  = (const float*)d_in[9];
  const float* b1  = (const float*)d_in[10];
  const float* w2  = (const float*)d_in[11];
  const float* b2  = (const float*)d_in[12];
  float* out = (float*)d_out;
  const int B = out_size;  // 2048

  mdtnn_phA_mfma<<<dim3(B), dim3(256), 0, stream>>>(D, sz, dfw, dfb, (uint2*)d_ws);
  mdtnn_phB5<<<dim3(B), dim3(128), 0, stream>>>(Z, sz, emb, cfw, cfb, fcw,
                                                w1, b1, w2, b2,
                                                (const unsigned*)d_ws, out);
}